// Round 5
// baseline (382.773 us; speedup 1.0000x reference)
//
#include <hip/hip_runtime.h>
#include <math.h>

#define WDIM 4096
#define SDIM 4096
#define NKEYS 1024
#define SHARP 10.0f

typedef float v4 __attribute__((ext_vector_type(4)));

__device__ __forceinline__ float wave_reduce_sum(float v) {
#pragma unroll
    for (int off = 32; off > 0; off >>= 1) v += __shfl_down(v, off, 64);
    return v;
}

// K1: noisy_mix[w] = sum_s holo[w,s] * conj(cue[w,s])
// One row per 256-thread block. NT cue loads (A/B: NT ~73 us vs plain 101),
// cue (HBM) issued before holo (L3-hit). 73 us == 128 MiB cue / 1.75 TB/s:
// kernel is 100% cue-stream-bound; holo L3 reads fully hidden. UNCHANGED.
// re = hr*cr + hi*ci ; im = hi*cr - hr*ci
__global__ __launch_bounds__(256) void k_mix(
    const float* __restrict__ hr, const float* __restrict__ hi,
    const float* __restrict__ cr, const float* __restrict__ ci,
    float* __restrict__ mix_re, float* __restrict__ mix_im) {
    const int w = blockIdx.x;
    const int t = threadIdx.x;
    const int wave = t >> 6, lane = t & 63;
    const size_t base = (size_t)w * SDIM;
    const v4* hr4 = (const v4*)(hr + base);
    const v4* hi4 = (const v4*)(hi + base);
    const v4* cr4 = (const v4*)(cr + base);
    const v4* ci4 = (const v4*)(ci + base);
    v4 a[4], b[4], c[4], d[4];
#pragma unroll
    for (int j = 0; j < 4; ++j) {
        const int idx = t + j * 256;
        c[j] = __builtin_nontemporal_load(cr4 + idx);
        d[j] = __builtin_nontemporal_load(ci4 + idx);
    }
#pragma unroll
    for (int j = 0; j < 4; ++j) {
        const int idx = t + j * 256;
        a[j] = hr4[idx];
        b[j] = hi4[idx];
    }
    float sr = 0.f, si = 0.f;
#pragma unroll
    for (int j = 0; j < 4; ++j) {
        sr += a[j].x * c[j].x + b[j].x * d[j].x;  si += b[j].x * c[j].x - a[j].x * d[j].x;
        sr += a[j].y * c[j].y + b[j].y * d[j].y;  si += b[j].y * c[j].y - a[j].y * d[j].y;
        sr += a[j].z * c[j].z + b[j].z * d[j].z;  si += b[j].z * c[j].z - a[j].z * d[j].z;
        sr += a[j].w * c[j].w + b[j].w * d[j].w;  si += b[j].w * c[j].w - a[j].w * d[j].w;
    }
    sr = wave_reduce_sum(sr);
    si = wave_reduce_sum(si);
    __shared__ float rr[4], ri[4];
    if (lane == 0) { rr[wave] = sr; ri[wave] = si; }
    __syncthreads();
    if (t == 0) {
        mix_re[w] = rr[0] + rr[1] + rr[2] + rr[3];
        mix_im[w] = ri[0] + ri[1] + ri[2] + ri[3];
    }
}

// K2: corr[n] = |sum_w keys[n,w] * mix[w]| * SHARP (plain dot, NO conjugation)
// One key per 256-thread block. Keys loaded PLAIN on purpose: they are
// re-read by k_clean and across iterations -> want L3 allocation.
__global__ __launch_bounds__(256) void k_corr(
    const float* __restrict__ kr, const float* __restrict__ ki,
    const float* __restrict__ mr, const float* __restrict__ mi,
    float* __restrict__ corr) {
    const int n = blockIdx.x;
    const int t = threadIdx.x;
    const int wave = t >> 6, lane = t & 63;
    const size_t base = (size_t)n * WDIM;
    const v4* kr4 = (const v4*)(kr + base);
    const v4* ki4 = (const v4*)(ki + base);
    const v4* mr4 = (const v4*)mr;
    const v4* mi4 = (const v4*)mi;
    v4 a[4], b[4], m[4], q[4];
#pragma unroll
    for (int j = 0; j < 4; ++j) {
        const int idx = t + j * 256;
        a[j] = kr4[idx];
        b[j] = ki4[idx];
        m[j] = mr4[idx];
        q[j] = mi4[idx];
    }
    float zr = 0.f, zi = 0.f;
#pragma unroll
    for (int j = 0; j < 4; ++j) {
        zr += a[j].x * m[j].x - b[j].x * q[j].x;  zi += a[j].x * q[j].x + b[j].x * m[j].x;
        zr += a[j].y * m[j].y - b[j].y * q[j].y;  zi += a[j].y * q[j].y + b[j].y * m[j].y;
        zr += a[j].z * m[j].z - b[j].z * q[j].z;  zi += a[j].z * q[j].z + b[j].z * m[j].z;
        zr += a[j].w * m[j].w - b[j].w * q[j].w;  zi += a[j].w * q[j].w + b[j].w * m[j].w;
    }
    zr = wave_reduce_sum(zr);
    zi = wave_reduce_sum(zi);
    __shared__ float rr[4], ri[4];
    if (lane == 0) { rr[wave] = zr; ri[wave] = zi; }
    __syncthreads();
    if (t == 0) {
        const float fr = rr[0] + rr[1] + rr[2] + rr[3];
        const float fi = ri[0] + ri[1] + ri[2] + ri[3];
        corr[n] = sqrtf(fr * fr + fi * fi) * SHARP;
    }
}

// K3+K4 fused: each block recomputes the 1024-wide softmax from corr
// (4 KB L2-hit read, fully parallel), then does its 16-key partial of
// clean_key[w] = sum_n att[n]*keys[n,w], atomicAdd into zeroed cre/cim.
__global__ __launch_bounds__(256) void k_clean(
    const float* __restrict__ kr, const float* __restrict__ ki,
    const float* __restrict__ corr,
    float* __restrict__ clean_re, float* __restrict__ clean_im) {
    const int t = threadIdx.x;
    __shared__ float red[256];
    __shared__ float satt[16];

    // --- softmax over the 1024 logits (redundant per block, cheap) ---
    float v0 = corr[t], v1 = corr[t + 256], v2 = corr[t + 512], v3 = corr[t + 768];
    float m = fmaxf(fmaxf(v0, v1), fmaxf(v2, v3));
    red[t] = m; __syncthreads();
    for (int s = 128; s > 0; s >>= 1) {
        if (t < s) red[t] = fmaxf(red[t], red[t + s]);
        __syncthreads();
    }
    const float mx = red[0];
    __syncthreads();
    float sum = expf(v0 - mx) + expf(v1 - mx) + expf(v2 - mx) + expf(v3 - mx);
    red[t] = sum; __syncthreads();
    for (int s = 128; s > 0; s >>= 1) {
        if (t < s) red[t] += red[t + s];
        __syncthreads();
    }
    const float inv = 1.0f / red[0];
    const int n0 = blockIdx.y * 16;
    if (t < 16) satt[t] = expf(corr[n0 + t] - mx) * inv;
    __syncthreads();

    // --- 16-key partial column sums ---
    const int wt = blockIdx.x;            // 0..3
    const int f4 = wt * 256 + t;
    float arx = 0.f, ary = 0.f, arz = 0.f, arw = 0.f;
    float aix = 0.f, aiy = 0.f, aiz = 0.f, aiw = 0.f;
#pragma unroll 1
    for (int jt = 0; jt < 4; ++jt) {
        v4 x[4], y[4]; float a[4];
#pragma unroll
        for (int j = 0; j < 4; ++j) {
            const int n = n0 + jt * 4 + j;
            a[j] = satt[jt * 4 + j];
            x[j] = ((const v4*)(kr + (size_t)n * WDIM))[f4];
            y[j] = ((const v4*)(ki + (size_t)n * WDIM))[f4];
        }
#pragma unroll
        for (int j = 0; j < 4; ++j) {
            arx += a[j] * x[j].x; ary += a[j] * x[j].y; arz += a[j] * x[j].z; arw += a[j] * x[j].w;
            aix += a[j] * y[j].x; aiy += a[j] * y[j].y; aiz += a[j] * y[j].z; aiw += a[j] * y[j].w;
        }
    }
    const int w = f4 * 4;
    atomicAdd(&clean_re[w + 0], arx); atomicAdd(&clean_re[w + 1], ary);
    atomicAdd(&clean_re[w + 2], arz); atomicAdd(&clean_re[w + 3], arw);
    atomicAdd(&clean_im[w + 0], aix); atomicAdd(&clean_im[w + 1], aiy);
    atomicAdd(&clean_im[w + 2], aiz); atomicAdd(&clean_im[w + 3], aiw);
}

// K5: out = holo * clean_key[w] — persistent grid-stride, depth-2 pipeline.
// THIS ROUND'S experiment (single-variable): (a) holo loads NT — the one
// measured strong lever (k_mix: NT reads 25-40% faster than plain); last use
// of holo, so no reuse lost IF NT hits-without-allocating in L3. (b) all 8
// per-chunk cre/cim coefficient pairs hoisted out of the streaming loop so
// the loop's critical path is pure load->fma->store.
// out_re = hr*a - hi*b ; out_im = hr*b + hi*a
#define KOUT_BLOCKS 2048
#define KOUT_THREADS ((size_t)KOUT_BLOCKS * 256)   // 524288
#define KOUT_CHUNKS 8                               // 4M v4 / 524288
__global__ __launch_bounds__(256) void k_out(
    const float* __restrict__ hr, const float* __restrict__ hi,
    const float* __restrict__ cre, const float* __restrict__ cim,
    float* __restrict__ out_re, float* __restrict__ out_im) {
    const v4* hr4 = (const v4*)hr;
    const v4* hi4 = (const v4*)hi;
    v4* or4 = (v4*)out_re;
    v4* oi4 = (v4*)out_im;
    const size_t g = (size_t)blockIdx.x * 256 + threadIdx.x;

    // hoist coefficients: chunk c covers row w = (g + c*524288)>>10
    float ca[KOUT_CHUNKS], cb[KOUT_CHUNKS];
#pragma unroll
    for (int c = 0; c < KOUT_CHUNKS; ++c) {
        const int w = (int)((g + (size_t)c * KOUT_THREADS) >> 10);
        ca[c] = cre[w];
        cb[c] = cim[w];
    }

    // prologue: chunk 0 loads in flight
    v4 h0 = __builtin_nontemporal_load(hr4 + g);
    v4 g0 = __builtin_nontemporal_load(hi4 + g);
    size_t gcur = g;
#pragma unroll 1
    for (int c = 1; c < KOUT_CHUNKS; ++c) {
        const size_t gn = g + (size_t)c * KOUT_THREADS;
        // issue next chunk's loads before consuming current
        v4 h1 = __builtin_nontemporal_load(hr4 + gn);
        v4 g1 = __builtin_nontemporal_load(hi4 + gn);
        const float a = ca[c - 1], b = cb[c - 1];
        v4 orr, oii;
        orr.x = h0.x * a - g0.x * b;  oii.x = h0.x * b + g0.x * a;
        orr.y = h0.y * a - g0.y * b;  oii.y = h0.y * b + g0.y * a;
        orr.z = h0.z * a - g0.z * b;  oii.z = h0.z * b + g0.z * a;
        orr.w = h0.w * a - g0.w * b;  oii.w = h0.w * b + g0.w * a;
        or4[gcur] = orr;
        oi4[gcur] = oii;
        h0 = h1; g0 = g1; gcur = gn;
    }
    // epilogue: last chunk
    {
        const float a = ca[KOUT_CHUNKS - 1], b = cb[KOUT_CHUNKS - 1];
        v4 orr, oii;
        orr.x = h0.x * a - g0.x * b;  oii.x = h0.x * b + g0.x * a;
        orr.y = h0.y * a - g0.y * b;  oii.y = h0.y * b + g0.y * a;
        orr.z = h0.z * a - g0.z * b;  oii.z = h0.z * b + g0.z * a;
        orr.w = h0.w * a - g0.w * b;  oii.w = h0.w * b + g0.w * a;
        or4[gcur] = orr;
        oi4[gcur] = oii;
    }
}

extern "C" void kernel_launch(void* const* d_in, const int* in_sizes, int n_in,
                              void* d_out, int out_size, void* d_ws, size_t ws_size,
                              hipStream_t stream) {
    const float* hr = (const float*)d_in[0];
    const float* hi = (const float*)d_in[1];
    const float* cr = (const float*)d_in[2];
    const float* ci = (const float*)d_in[3];
    const float* kr = (const float*)d_in[4];
    const float* ki = (const float*)d_in[5];

    float* ws = (float*)d_ws;
    float* mix_re = ws;                 // 4096
    float* mix_im = ws + 4096;          // 4096
    float* corr   = ws + 8192;          // 1024
    float* cre    = ws + 10240;         // 4096
    float* cim    = ws + 14336;         // 4096 (contiguous with cre)

    float* out_re = (float*)d_out;
    float* out_im = out_re + (size_t)WDIM * SDIM;

    // memset first: off the dependency chain until k_clean needs it
    hipMemsetAsync(cre, 0, 2 * WDIM * sizeof(float), stream);
    k_mix<<<WDIM, 256, 0, stream>>>(hr, hi, cr, ci, mix_re, mix_im);
    k_corr<<<NKEYS, 256, 0, stream>>>(kr, ki, mix_re, mix_im, corr);
    k_clean<<<dim3(4, 64), 256, 0, stream>>>(kr, ki, corr, cre, cim);
    k_out<<<KOUT_BLOCKS, 256, 0, stream>>>(hr, hi, cre, cim, out_re, out_im);
}

// Round 6
// 366.597 us; speedup vs baseline: 1.0441x; 1.0441x over previous
//
#include <hip/hip_runtime.h>
#include <math.h>

#define WDIM 4096
#define SDIM 4096
#define NKEYS 1024
#define SHARP 10.0f

typedef float v4 __attribute__((ext_vector_type(4)));

__device__ __forceinline__ float wave_reduce_sum(float v) {
#pragma unroll
    for (int off = 32; off > 0; off >>= 1) v += __shfl_down(v, off, 64);
    return v;
}

// K1: noisy_mix[w] = sum_s holo[w,s] * conj(cue[w,s])
// One row per 256-thread block. NT cue loads (A/B: NT ~73 us vs plain 101),
// cue (HBM) issued before holo (L3-hit). 73 us = 256 MiB reads / 3.5 TB/s
// = 14.4 GB/s/CU read, above the m13 copy read rate -> at the read wall.
// re = hr*cr + hi*ci ; im = hi*cr - hr*ci
__global__ __launch_bounds__(256) void k_mix(
    const float* __restrict__ hr, const float* __restrict__ hi,
    const float* __restrict__ cr, const float* __restrict__ ci,
    float* __restrict__ mix_re, float* __restrict__ mix_im) {
    const int w = blockIdx.x;
    const int t = threadIdx.x;
    const int wave = t >> 6, lane = t & 63;
    const size_t base = (size_t)w * SDIM;
    const v4* hr4 = (const v4*)(hr + base);
    const v4* hi4 = (const v4*)(hi + base);
    const v4* cr4 = (const v4*)(cr + base);
    const v4* ci4 = (const v4*)(ci + base);
    v4 a[4], b[4], c[4], d[4];
#pragma unroll
    for (int j = 0; j < 4; ++j) {
        const int idx = t + j * 256;
        c[j] = __builtin_nontemporal_load(cr4 + idx);
        d[j] = __builtin_nontemporal_load(ci4 + idx);
    }
#pragma unroll
    for (int j = 0; j < 4; ++j) {
        const int idx = t + j * 256;
        a[j] = hr4[idx];
        b[j] = hi4[idx];
    }
    float sr = 0.f, si = 0.f;
#pragma unroll
    for (int j = 0; j < 4; ++j) {
        sr += a[j].x * c[j].x + b[j].x * d[j].x;  si += b[j].x * c[j].x - a[j].x * d[j].x;
        sr += a[j].y * c[j].y + b[j].y * d[j].y;  si += b[j].y * c[j].y - a[j].y * d[j].y;
        sr += a[j].z * c[j].z + b[j].z * d[j].z;  si += b[j].z * c[j].z - a[j].z * d[j].z;
        sr += a[j].w * c[j].w + b[j].w * d[j].w;  si += b[j].w * c[j].w - a[j].w * d[j].w;
    }
    sr = wave_reduce_sum(sr);
    si = wave_reduce_sum(si);
    __shared__ float rr[4], ri[4];
    if (lane == 0) { rr[wave] = sr; ri[wave] = si; }
    __syncthreads();
    if (t == 0) {
        mix_re[w] = rr[0] + rr[1] + rr[2] + rr[3];
        mix_im[w] = ri[0] + ri[1] + ri[2] + ri[3];
    }
}

// K2: corr[n] = |sum_w keys[n,w] * mix[w]| * SHARP (plain dot, NO conjugation)
// One key per 256-thread block. Keys loaded PLAIN on purpose: re-read by
// k_clean and across iterations -> want L3 allocation.
__global__ __launch_bounds__(256) void k_corr(
    const float* __restrict__ kr, const float* __restrict__ ki,
    const float* __restrict__ mr, const float* __restrict__ mi,
    float* __restrict__ corr) {
    const int n = blockIdx.x;
    const int t = threadIdx.x;
    const int wave = t >> 6, lane = t & 63;
    const size_t base = (size_t)n * WDIM;
    const v4* kr4 = (const v4*)(kr + base);
    const v4* ki4 = (const v4*)(ki + base);
    const v4* mr4 = (const v4*)mr;
    const v4* mi4 = (const v4*)mi;
    v4 a[4], b[4], m[4], q[4];
#pragma unroll
    for (int j = 0; j < 4; ++j) {
        const int idx = t + j * 256;
        a[j] = kr4[idx];
        b[j] = ki4[idx];
        m[j] = mr4[idx];
        q[j] = mi4[idx];
    }
    float zr = 0.f, zi = 0.f;
#pragma unroll
    for (int j = 0; j < 4; ++j) {
        zr += a[j].x * m[j].x - b[j].x * q[j].x;  zi += a[j].x * q[j].x + b[j].x * m[j].x;
        zr += a[j].y * m[j].y - b[j].y * q[j].y;  zi += a[j].y * q[j].y + b[j].y * m[j].y;
        zr += a[j].z * m[j].z - b[j].z * q[j].z;  zi += a[j].z * q[j].z + b[j].z * m[j].z;
        zr += a[j].w * m[j].w - b[j].w * q[j].w;  zi += a[j].w * q[j].w + b[j].w * m[j].w;
    }
    zr = wave_reduce_sum(zr);
    zi = wave_reduce_sum(zi);
    __shared__ float rr[4], ri[4];
    if (lane == 0) { rr[wave] = zr; ri[wave] = zi; }
    __syncthreads();
    if (t == 0) {
        const float fr = rr[0] + rr[1] + rr[2] + rr[3];
        const float fi = ri[0] + ri[1] + ri[2] + ri[3];
        corr[n] = sqrtf(fr * fr + fi * fi) * SHARP;
    }
}

// K3+K4 fused: each block recomputes the 1024-wide softmax from corr
// (4 KB L2-hit read, fully parallel), then does its 16-key partial of
// clean_key[w] = sum_n att[n]*keys[n,w], atomicAdd into zeroed cre/cim.
__global__ __launch_bounds__(256) void k_clean(
    const float* __restrict__ kr, const float* __restrict__ ki,
    const float* __restrict__ corr,
    float* __restrict__ clean_re, float* __restrict__ clean_im) {
    const int t = threadIdx.x;
    __shared__ float red[256];
    __shared__ float satt[16];

    // --- softmax over the 1024 logits (redundant per block, cheap) ---
    float v0 = corr[t], v1 = corr[t + 256], v2 = corr[t + 512], v3 = corr[t + 768];
    float m = fmaxf(fmaxf(v0, v1), fmaxf(v2, v3));
    red[t] = m; __syncthreads();
    for (int s = 128; s > 0; s >>= 1) {
        if (t < s) red[t] = fmaxf(red[t], red[t + s]);
        __syncthreads();
    }
    const float mx = red[0];
    __syncthreads();
    float sum = expf(v0 - mx) + expf(v1 - mx) + expf(v2 - mx) + expf(v3 - mx);
    red[t] = sum; __syncthreads();
    for (int s = 128; s > 0; s >>= 1) {
        if (t < s) red[t] += red[t + s];
        __syncthreads();
    }
    const float inv = 1.0f / red[0];
    const int n0 = blockIdx.y * 16;
    if (t < 16) satt[t] = expf(corr[n0 + t] - mx) * inv;
    __syncthreads();

    // --- 16-key partial column sums ---
    const int wt = blockIdx.x;            // 0..3
    const int f4 = wt * 256 + t;
    float arx = 0.f, ary = 0.f, arz = 0.f, arw = 0.f;
    float aix = 0.f, aiy = 0.f, aiz = 0.f, aiw = 0.f;
#pragma unroll 1
    for (int jt = 0; jt < 4; ++jt) {
        v4 x[4], y[4]; float a[4];
#pragma unroll
        for (int j = 0; j < 4; ++j) {
            const int n = n0 + jt * 4 + j;
            a[j] = satt[jt * 4 + j];
            x[j] = ((const v4*)(kr + (size_t)n * WDIM))[f4];
            y[j] = ((const v4*)(ki + (size_t)n * WDIM))[f4];
        }
#pragma unroll
        for (int j = 0; j < 4; ++j) {
            arx += a[j] * x[j].x; ary += a[j] * x[j].y; arz += a[j] * x[j].z; arw += a[j] * x[j].w;
            aix += a[j] * y[j].x; aiy += a[j] * y[j].y; aiz += a[j] * y[j].z; aiw += a[j] * y[j].w;
        }
    }
    const int w = f4 * 4;
    atomicAdd(&clean_re[w + 0], arx); atomicAdd(&clean_re[w + 1], ary);
    atomicAdd(&clean_re[w + 2], arz); atomicAdd(&clean_re[w + 3], arw);
    atomicAdd(&clean_im[w + 0], aix); atomicAdd(&clean_im[w + 1], aiy);
    atomicAdd(&clean_im[w + 2], aiz); atomicAdd(&clean_im[w + 3], aiw);
}

// K5: out = holo * clean_key[w] — RESTORED to the r1 best-measured form:
// one block/row, 8 loads up front, plain holo loads (L3-hit), NT stores
// (best total 364.9 us). Grid-stride/pipelined/NT-load variants all landed
// 72-80 us (= ~14 GB/s/CU mixed, the same streaming wall) — reverted.
// out_re = hr*a - hi*b ; out_im = hr*b + hi*a
__global__ __launch_bounds__(256) void k_out(
    const float* __restrict__ hr, const float* __restrict__ hi,
    const float* __restrict__ cre, const float* __restrict__ cim,
    float* __restrict__ out_re, float* __restrict__ out_im) {
    const int w = blockIdx.x;
    const size_t base = (size_t)w * SDIM;
    const float a = cre[w], b = cim[w];
    const v4* hr4 = (const v4*)(hr + base);
    const v4* hi4 = (const v4*)(hi + base);
    v4* or4 = (v4*)(out_re + base);
    v4* oi4 = (v4*)(out_im + base);
    v4 h[4], g[4];
#pragma unroll
    for (int j = 0; j < 4; ++j) {
        const int i = threadIdx.x + j * 256;
        h[j] = hr4[i];
        g[j] = hi4[i];
    }
#pragma unroll
    for (int j = 0; j < 4; ++j) {
        const int i = threadIdx.x + j * 256;
        v4 orr, oii;
        orr.x = h[j].x * a - g[j].x * b;  oii.x = h[j].x * b + g[j].x * a;
        orr.y = h[j].y * a - g[j].y * b;  oii.y = h[j].y * b + g[j].y * a;
        orr.z = h[j].z * a - g[j].z * b;  oii.z = h[j].z * b + g[j].z * a;
        orr.w = h[j].w * a - g[j].w * b;  oii.w = h[j].w * b + g[j].w * a;
        __builtin_nontemporal_store(orr, or4 + i);
        __builtin_nontemporal_store(oii, oi4 + i);
    }
}

extern "C" void kernel_launch(void* const* d_in, const int* in_sizes, int n_in,
                              void* d_out, int out_size, void* d_ws, size_t ws_size,
                              hipStream_t stream) {
    const float* hr = (const float*)d_in[0];
    const float* hi = (const float*)d_in[1];
    const float* cr = (const float*)d_in[2];
    const float* ci = (const float*)d_in[3];
    const float* kr = (const float*)d_in[4];
    const float* ki = (const float*)d_in[5];

    float* ws = (float*)d_ws;
    float* mix_re = ws;                 // 4096
    float* mix_im = ws + 4096;          // 4096
    float* corr   = ws + 8192;          // 1024
    float* cre    = ws + 10240;         // 4096
    float* cim    = ws + 14336;         // 4096 (contiguous with cre)

    float* out_re = (float*)d_out;
    float* out_im = out_re + (size_t)WDIM * SDIM;

    // memset first: off the dependency chain until k_clean needs it
    hipMemsetAsync(cre, 0, 2 * WDIM * sizeof(float), stream);
    k_mix<<<WDIM, 256, 0, stream>>>(hr, hi, cr, ci, mix_re, mix_im);
    k_corr<<<NKEYS, 256, 0, stream>>>(kr, ki, mix_re, mix_im, corr);
    k_clean<<<dim3(4, 64), 256, 0, stream>>>(kr, ki, corr, cre, cim);
    k_out<<<WDIM, 256, 0, stream>>>(hr, hi, cre, cim, out_re, out_im);
}

// Round 7
// 358.750 us; speedup vs baseline: 1.0670x; 1.0219x over previous
//
#include <hip/hip_runtime.h>
#include <math.h>

#define WDIM 4096
#define SDIM 4096
#define NKEYS 1024
#define SHARP 10.0f

typedef float v4 __attribute__((ext_vector_type(4)));

__device__ __forceinline__ float wave_reduce_sum(float v) {
#pragma unroll
    for (int off = 32; off > 0; off >>= 1) v += __shfl_down(v, off, 64);
    return v;
}

// K1: noisy_mix[w] = sum_s holo[w,s] * conj(cue[w,s])
// EXPERIMENT (r7): holo loads are now ALSO NT, so holo never allocates in
// L3 and is read as an HBM stream everywhere. Cross-kernel evidence says
// L3-HIT reads run at only ~1.75 TB/s (k_mix holo, k_out holo) while HBM
// streams reach 3.15-6.7 TB/s (m13 copy read share, fill writes). Keeping
// holo HBM-resident should let both k_mix and k_out stream faster.
// re = hr*cr + hi*ci ; im = hi*cr - hr*ci
__global__ __launch_bounds__(256) void k_mix(
    const float* __restrict__ hr, const float* __restrict__ hi,
    const float* __restrict__ cr, const float* __restrict__ ci,
    float* __restrict__ mix_re, float* __restrict__ mix_im) {
    const int w = blockIdx.x;
    const int t = threadIdx.x;
    const int wave = t >> 6, lane = t & 63;
    const size_t base = (size_t)w * SDIM;
    const v4* hr4 = (const v4*)(hr + base);
    const v4* hi4 = (const v4*)(hi + base);
    const v4* cr4 = (const v4*)(cr + base);
    const v4* ci4 = (const v4*)(ci + base);
    v4 a[4], b[4], c[4], d[4];
#pragma unroll
    for (int j = 0; j < 4; ++j) {
        const int idx = t + j * 256;
        c[j] = __builtin_nontemporal_load(cr4 + idx);
        d[j] = __builtin_nontemporal_load(ci4 + idx);
    }
#pragma unroll
    for (int j = 0; j < 4; ++j) {
        const int idx = t + j * 256;
        a[j] = __builtin_nontemporal_load(hr4 + idx);
        b[j] = __builtin_nontemporal_load(hi4 + idx);
    }
    float sr = 0.f, si = 0.f;
#pragma unroll
    for (int j = 0; j < 4; ++j) {
        sr += a[j].x * c[j].x + b[j].x * d[j].x;  si += b[j].x * c[j].x - a[j].x * d[j].x;
        sr += a[j].y * c[j].y + b[j].y * d[j].y;  si += b[j].y * c[j].y - a[j].y * d[j].y;
        sr += a[j].z * c[j].z + b[j].z * d[j].z;  si += b[j].z * c[j].z - a[j].z * d[j].z;
        sr += a[j].w * c[j].w + b[j].w * d[j].w;  si += b[j].w * c[j].w - a[j].w * d[j].w;
    }
    sr = wave_reduce_sum(sr);
    si = wave_reduce_sum(si);
    __shared__ float rr[4], ri[4];
    if (lane == 0) { rr[wave] = sr; ri[wave] = si; }
    __syncthreads();
    if (t == 0) {
        mix_re[w] = rr[0] + rr[1] + rr[2] + rr[3];
        mix_im[w] = ri[0] + ri[1] + ri[2] + ri[3];
    }
}

// K2: corr[n] = |sum_w keys[n,w] * mix[w]| * SHARP (plain dot, NO conjugation)
// One key per 256-thread block. Keys loaded PLAIN on purpose: small (32 MiB),
// re-read by k_clean and across iterations -> want L3 allocation.
__global__ __launch_bounds__(256) void k_corr(
    const float* __restrict__ kr, const float* __restrict__ ki,
    const float* __restrict__ mr, const float* __restrict__ mi,
    float* __restrict__ corr) {
    const int n = blockIdx.x;
    const int t = threadIdx.x;
    const int wave = t >> 6, lane = t & 63;
    const size_t base = (size_t)n * WDIM;
    const v4* kr4 = (const v4*)(kr + base);
    const v4* ki4 = (const v4*)(ki + base);
    const v4* mr4 = (const v4*)mr;
    const v4* mi4 = (const v4*)mi;
    v4 a[4], b[4], m[4], q[4];
#pragma unroll
    for (int j = 0; j < 4; ++j) {
        const int idx = t + j * 256;
        a[j] = kr4[idx];
        b[j] = ki4[idx];
        m[j] = mr4[idx];
        q[j] = mi4[idx];
    }
    float zr = 0.f, zi = 0.f;
#pragma unroll
    for (int j = 0; j < 4; ++j) {
        zr += a[j].x * m[j].x - b[j].x * q[j].x;  zi += a[j].x * q[j].x + b[j].x * m[j].x;
        zr += a[j].y * m[j].y - b[j].y * q[j].y;  zi += a[j].y * q[j].y + b[j].y * m[j].y;
        zr += a[j].z * m[j].z - b[j].z * q[j].z;  zi += a[j].z * q[j].z + b[j].z * m[j].z;
        zr += a[j].w * m[j].w - b[j].w * q[j].w;  zi += a[j].w * q[j].w + b[j].w * m[j].w;
    }
    zr = wave_reduce_sum(zr);
    zi = wave_reduce_sum(zi);
    __shared__ float rr[4], ri[4];
    if (lane == 0) { rr[wave] = zr; ri[wave] = zi; }
    __syncthreads();
    if (t == 0) {
        const float fr = rr[0] + rr[1] + rr[2] + rr[3];
        const float fi = ri[0] + ri[1] + ri[2] + ri[3];
        corr[n] = sqrtf(fr * fr + fi * fi) * SHARP;
    }
}

// K3+K4 fused: each block recomputes the 1024-wide softmax from corr
// (4 KB L2-hit read, fully parallel), then does its 16-key partial of
// clean_key[w] = sum_n att[n]*keys[n,w], atomicAdd into zeroed cre/cim.
__global__ __launch_bounds__(256) void k_clean(
    const float* __restrict__ kr, const float* __restrict__ ki,
    const float* __restrict__ corr,
    float* __restrict__ clean_re, float* __restrict__ clean_im) {
    const int t = threadIdx.x;
    __shared__ float red[256];
    __shared__ float satt[16];

    // --- softmax over the 1024 logits (redundant per block, cheap) ---
    float v0 = corr[t], v1 = corr[t + 256], v2 = corr[t + 512], v3 = corr[t + 768];
    float m = fmaxf(fmaxf(v0, v1), fmaxf(v2, v3));
    red[t] = m; __syncthreads();
    for (int s = 128; s > 0; s >>= 1) {
        if (t < s) red[t] = fmaxf(red[t], red[t + s]);
        __syncthreads();
    }
    const float mx = red[0];
    __syncthreads();
    float sum = expf(v0 - mx) + expf(v1 - mx) + expf(v2 - mx) + expf(v3 - mx);
    red[t] = sum; __syncthreads();
    for (int s = 128; s > 0; s >>= 1) {
        if (t < s) red[t] += red[t + s];
        __syncthreads();
    }
    const float inv = 1.0f / red[0];
    const int n0 = blockIdx.y * 16;
    if (t < 16) satt[t] = expf(corr[n0 + t] - mx) * inv;
    __syncthreads();

    // --- 16-key partial column sums ---
    const int wt = blockIdx.x;            // 0..3
    const int f4 = wt * 256 + t;
    float arx = 0.f, ary = 0.f, arz = 0.f, arw = 0.f;
    float aix = 0.f, aiy = 0.f, aiz = 0.f, aiw = 0.f;
#pragma unroll 1
    for (int jt = 0; jt < 4; ++jt) {
        v4 x[4], y[4]; float a[4];
#pragma unroll
        for (int j = 0; j < 4; ++j) {
            const int n = n0 + jt * 4 + j;
            a[j] = satt[jt * 4 + j];
            x[j] = ((const v4*)(kr + (size_t)n * WDIM))[f4];
            y[j] = ((const v4*)(ki + (size_t)n * WDIM))[f4];
        }
#pragma unroll
        for (int j = 0; j < 4; ++j) {
            arx += a[j] * x[j].x; ary += a[j] * x[j].y; arz += a[j] * x[j].z; arw += a[j] * x[j].w;
            aix += a[j] * y[j].x; aiy += a[j] * y[j].y; aiz += a[j] * y[j].z; aiw += a[j] * y[j].w;
        }
    }
    const int w = f4 * 4;
    atomicAdd(&clean_re[w + 0], arx); atomicAdd(&clean_re[w + 1], ary);
    atomicAdd(&clean_re[w + 2], arz); atomicAdd(&clean_re[w + 3], arw);
    atomicAdd(&clean_im[w + 0], aix); atomicAdd(&clean_im[w + 1], aiy);
    atomicAdd(&clean_im[w + 2], aiz); atomicAdd(&clean_im[w + 3], aiw);
}

// K5: out = holo * clean_key[w] — r1 structure (one block/row, NT stores),
// but holo loads now NT: with k_mix also reading holo NT, holo stays
// HBM-resident and this read should stream at HBM rate (~3+ TB/s) instead
// of the measured ~1.75 TB/s L3-hit rate.
// out_re = hr*a - hi*b ; out_im = hr*b + hi*a
__global__ __launch_bounds__(256) void k_out(
    const float* __restrict__ hr, const float* __restrict__ hi,
    const float* __restrict__ cre, const float* __restrict__ cim,
    float* __restrict__ out_re, float* __restrict__ out_im) {
    const int w = blockIdx.x;
    const size_t base = (size_t)w * SDIM;
    const float a = cre[w], b = cim[w];
    const v4* hr4 = (const v4*)(hr + base);
    const v4* hi4 = (const v4*)(hi + base);
    v4* or4 = (v4*)(out_re + base);
    v4* oi4 = (v4*)(out_im + base);
    v4 h[4], g[4];
#pragma unroll
    for (int j = 0; j < 4; ++j) {
        const int i = threadIdx.x + j * 256;
        h[j] = __builtin_nontemporal_load(hr4 + i);
        g[j] = __builtin_nontemporal_load(hi4 + i);
    }
#pragma unroll
    for (int j = 0; j < 4; ++j) {
        const int i = threadIdx.x + j * 256;
        v4 orr, oii;
        orr.x = h[j].x * a - g[j].x * b;  oii.x = h[j].x * b + g[j].x * a;
        orr.y = h[j].y * a - g[j].y * b;  oii.y = h[j].y * b + g[j].y * a;
        orr.z = h[j].z * a - g[j].z * b;  oii.z = h[j].z * b + g[j].z * a;
        orr.w = h[j].w * a - g[j].w * b;  oii.w = h[j].w * b + g[j].w * a;
        __builtin_nontemporal_store(orr, or4 + i);
        __builtin_nontemporal_store(oii, oi4 + i);
    }
}

extern "C" void kernel_launch(void* const* d_in, const int* in_sizes, int n_in,
                              void* d_out, int out_size, void* d_ws, size_t ws_size,
                              hipStream_t stream) {
    const float* hr = (const float*)d_in[0];
    const float* hi = (const float*)d_in[1];
    const float* cr = (const float*)d_in[2];
    const float* ci = (const float*)d_in[3];
    const float* kr = (const float*)d_in[4];
    const float* ki = (const float*)d_in[5];

    float* ws = (float*)d_ws;
    float* mix_re = ws;                 // 4096
    float* mix_im = ws + 4096;          // 4096
    float* corr   = ws + 8192;          // 1024
    float* cre    = ws + 10240;         // 4096
    float* cim    = ws + 14336;         // 4096 (contiguous with cre)

    float* out_re = (float*)d_out;
    float* out_im = out_re + (size_t)WDIM * SDIM;

    // memset first: off the dependency chain until k_clean needs it
    hipMemsetAsync(cre, 0, 2 * WDIM * sizeof(float), stream);
    k_mix<<<WDIM, 256, 0, stream>>>(hr, hi, cr, ci, mix_re, mix_im);
    k_corr<<<NKEYS, 256, 0, stream>>>(kr, ki, mix_re, mix_im, corr);
    k_clean<<<dim3(4, 64), 256, 0, stream>>>(kr, ki, corr, cre, cim);
    k_out<<<WDIM, 256, 0, stream>>>(hr, hi, cre, cim, out_re, out_im);
}